// Round 16
// baseline (287.075 us; speedup 1.0000x reference)
//
#include <hip/hip_runtime.h>

#define N_NODES  100000
#define N_EDGES  1600000
#define D        128
#define NFB      3125         // fine buckets of 32 nodes (100000/32, exact)
#define SUBCAP   768          // fine capacity (avg 512, 11 sigma)
#define OCAP     8192         // overflow backstop
#define FCHUNK   8192         // edges per fill block -> 196 blocks
#define FILL_BLOCKS ((N_EDGES + FCHUNK - 1) / FCHUNK)   // 196
#define NPACK    ((NFB + 1) / 2)                        // packed u32 counters
#define NCUR     (NFB + 3)                              // cursors (+pad)

typedef __attribute__((ext_vector_type(8))) short bf16x8;
typedef __attribute__((ext_vector_type(4))) float f32x4;

// f32 -> bf16 (round-to-nearest-even)
__device__ __forceinline__ unsigned short f2bf(float x) {
    unsigned u = __float_as_uint(x);
    u += 0x7fffu + ((u >> 16) & 1u);
    return (unsigned short)(u >> 16);
}

// ---------------------------------------------------------------------------
// 0) init: zero ccursor+oflow_cnt AND pack W into B-fragment order
// ---------------------------------------------------------------------------
__global__ __launch_bounds__(256) void init_kernel(
    const float* __restrict__ W, unsigned short* __restrict__ Wfrag,
    int* __restrict__ ccursor)
{
    int t = blockIdx.x * 256 + threadIdx.x;
    if (t <= NCUR) ccursor[t] = 0;              // cursors + oflow_cnt
    int k = t >> 7, n = t & 127;
    int c = n >> 4, cc = n & 15, ks = k >> 5, g = (k >> 3) & 3, j = k & 7;
    int lane = g * 16 + cc;
    Wfrag[(size_t)(((c * 4 + ks) * 64) + lane) * 8 + j] = f2bf(W[t]);
}

// ---------------------------------------------------------------------------
// 1) fill direct 32-node buckets with ONE int per edge:
//    e = dst(17b) | src_local(5b)<<17 | val_q10<<22.  1024 thr, R13-proven shape.
// ---------------------------------------------------------------------------
__global__ __launch_bounds__(1024) void fill_fine(
    const int* __restrict__ src, const int* __restrict__ dst,
    const float* __restrict__ vals, int* __restrict__ ccursor,
    int* __restrict__ sedge, int4* __restrict__ oflow,
    int* __restrict__ oflow_cnt)
{
    __shared__ unsigned lhistP[NPACK];
    __shared__ unsigned lbaseP[NPACK];
    const int t = threadIdx.x;

    for (int i = t; i < NPACK; i += 1024) lhistP[i] = 0;
    __syncthreads();
    const int e0 = blockIdx.x * FCHUNK;
    const int e1 = min(e0 + FCHUNK, N_EDGES);

    // phase 1: register-stage packed edges + packed local histogram
    int myS[8]; int myP[8]; float myV[8];
#pragma unroll
    for (int q = 0; q < 8; ++q) {
        int e = e0 + t + q * 1024;
        myS[q] = -1;
        if (e < e1) {
            int s = src[e];
            float v = vals[e];
            int qv = (int)(v * 1023.f + 0.5f);
            myS[q] = s;
            myV[q] = v;
            myP[q] = dst[e] | ((s & 31) << 17) | (qv << 22);
            int b = s >> 5;
            atomicAdd(&lhistP[b >> 1], 1u << ((b & 1) << 4));
        }
    }
    __syncthreads();
    // phase 2: reserve global ranges, reset local cursors
    for (int i = t; i < NPACK; i += 1024) {
        unsigned p = lhistP[i];
        unsigned c0 = p & 0xffffu, c1 = p >> 16;
        unsigned b0 = c0 ? (unsigned)atomicAdd(&ccursor[2 * i], (int)c0) : 0u;
        unsigned b1 = c1 ? (unsigned)atomicAdd(&ccursor[2 * i + 1], (int)c1) : 0u;
        lbaseP[i] = (b0 & 0xffffu) | (b1 << 16);
        lhistP[i] = 0;
    }
    __syncthreads();
    // phase 3: place from registers
#pragma unroll
    for (int q = 0; q < 8; ++q) {
        if (myS[q] >= 0) {
            int s = myS[q];
            int b = s >> 5;
            unsigned sh = (unsigned)(b & 1) << 4;
            unsigned old = atomicAdd(&lhistP[b >> 1], 1u << sh);
            int pos = (int)((lbaseP[b >> 1] >> sh) & 0xffffu) +
                      (int)((old >> sh) & 0xffffu);
            if (pos < SUBCAP) {
                sedge[(size_t)b * SUBCAP + pos] = myP[q];
            } else {
                int oc = atomicAdd(oflow_cnt, 1);
                if (oc < OCAP)
                    oflow[oc] = make_int4(s, myP[q] & 0x1FFFF,
                                          __float_as_int(myV[q]), 0);
            }
        }
    }
}

// ---------------------------------------------------------------------------
// 2) sort_bucket: counting-sort each bucket ONCE into sedge_s (global) and
//    emit per-node absolute offset + count. One WG per bucket.
// ---------------------------------------------------------------------------
__global__ __launch_bounds__(256) void sort_bucket(
    const int* __restrict__ sedge, const int* __restrict__ ccursor,
    int* __restrict__ sedge_s, int* __restrict__ off, int* __restrict__ cnt)
{
    __shared__ int h[32];
    __shared__ int ex[32];
    __shared__ int cur[32];
    const int bkt = blockIdx.x;
    const int t = threadIdx.x;
    const size_t base = (size_t)bkt * SUBCAP;
    const int n = min(ccursor[bkt], SUBCAP);

    if (t < 32) h[t] = 0;
    __syncthreads();
    int myE[3]; int myR[3];
#pragma unroll
    for (int q = 0; q < 3; ++q) {
        int j = t + q * 256;
        myR[q] = -1;
        if (j < n) {
            myE[q] = sedge[base + j];
            myR[q] = (myE[q] >> 17) & 31;
            atomicAdd(&h[myR[q]], 1);
        }
    }
    __syncthreads();
    if (t < 32) {
        int v = h[t];
        int x = v;
        for (int o = 1; o < 32; o <<= 1) {
            int y = __shfl_up(x, o);
            if (t >= o) x += y;
        }
        ex[t] = x - v;
        cur[t] = 0;
    }
    __syncthreads();
#pragma unroll
    for (int q = 0; q < 3; ++q) {
        if (myR[q] >= 0) {
            int pos = ex[myR[q]] + atomicAdd(&cur[myR[q]], 1);
            sedge_s[base + pos] = myE[q];
        }
    }
    if (t < 32) {
        int node = bkt * 32 + t;
        off[node] = (int)base + ex[t];
        cnt[node] = h[t];
    }
}

// ---------------------------------------------------------------------------
// 3) HW = H @ W via MFMA, output in PANEL layout:
//    HWp[panel c][node][16 cols] = HWp[((c*N + row)*16 + col16]  (3.2 MB/panel)
// ---------------------------------------------------------------------------
__global__ __launch_bounds__(256) void gemm_mfma(
    const float* __restrict__ H, const unsigned short* __restrict__ Wfrag,
    unsigned short* __restrict__ HWp)
{
    const int wid  = threadIdx.x >> 6;
    const int lane = threadIdx.x & 63;
    const int row16 = blockIdx.x * 64 + wid * 16;
    const int g = lane >> 4;

    int arow = row16 + (lane & 15);
    if (arow >= N_NODES) arow = N_NODES - 1;   // clamp (dup read, never stored)

    f32x4 acc[8];
#pragma unroll
    for (int c = 0; c < 8; ++c) acc[c] = (f32x4){0.f, 0.f, 0.f, 0.f};

#pragma unroll
    for (int ks = 0; ks < 4; ++ks) {
        const float* ap = H + (size_t)arow * D + ks * 32 + g * 8;
        float4 a0 = *reinterpret_cast<const float4*>(ap);
        float4 a1 = *reinterpret_cast<const float4*>(ap + 4);
        bf16x8 af;
        af[0] = (short)f2bf(a0.x); af[1] = (short)f2bf(a0.y);
        af[2] = (short)f2bf(a0.z); af[3] = (short)f2bf(a0.w);
        af[4] = (short)f2bf(a1.x); af[5] = (short)f2bf(a1.y);
        af[6] = (short)f2bf(a1.z); af[7] = (short)f2bf(a1.w);
#pragma unroll
        for (int c = 0; c < 8; ++c) {
            bf16x8 bf = *reinterpret_cast<const bf16x8*>(
                Wfrag + (size_t)((c * 4 + ks) * 64 + lane) * 8);
            acc[c] = __builtin_amdgcn_mfma_f32_16x16x32_bf16(af, bf, acc[c], 0, 0, 0);
        }
    }

#pragma unroll
    for (int c = 0; c < 8; ++c) {
#pragma unroll
        for (int r = 0; r < 4; ++r) {
            int orow = row16 + g * 4 + r;
            if (orow < N_NODES)
                HWp[((size_t)c * N_NODES + orow) * 16 + (lane & 15)] = f2bf(acc[c][r]);
        }
    }
}

// ---------------------------------------------------------------------------
// 4) panel_gather: grid = NFB*8; p = blockIdx&7 (-> XCD p under round-robin),
//    bkt = blockIdx>>3. Each block computes the 16-col panel-p slice of its
//    bucket's 32 output rows. Panel (3.2 MB) stays L2-resident per XCD.
//    Per edge: 8 lanes x 2 cols; shfl_xor reduce over the 8 edge slots.
//    No LDS, no barriers.
// ---------------------------------------------------------------------------
__global__ __launch_bounds__(256) void panel_gather(
    const unsigned short* __restrict__ HWp, const int* __restrict__ sedge_s,
    const int* __restrict__ off, const int* __restrict__ cnt,
    const int4* __restrict__ oflow, const int* __restrict__ oflow_cnt,
    const float* __restrict__ bias, float* __restrict__ out)
{
    const int bkt = blockIdx.x >> 3;
    const int p   = blockIdx.x & 7;
    const int t   = threadIdx.x;
    const int wid = t >> 6, lane = t & 63;
    const int g   = lane >> 3;          // edge slot 0..7
    const int cc  = lane & 7;           // col pair 0..7
    const unsigned short* pan = HWp + (size_t)p * N_NODES * 16;
    const float2 bv = *reinterpret_cast<const float2*>(bias + p * 16 + cc * 2);
    const int ovc = *oflow_cnt;         // normally 0
    const float inv1023 = 1.0f / 1023.0f;

    for (int ln = wid; ln < 32; ln += 4) {
        const int node = bkt * 32 + ln;
        const int j0 = off[node], dg = cnt[node];
        float sx = 0.f, sy = 0.f;
        for (int j = 0; j < dg; j += 8) {
            int idx = j + g;
            int e = 0;
            if (idx < dg) e = sedge_s[j0 + idx];
            float v = (float)((unsigned)e >> 22) * inv1023;   // 0 when inactive
            int dn = e & 0x1FFFF;
            unsigned u = *reinterpret_cast<const unsigned*>(pan + (size_t)dn * 16 + cc * 2);
            sx += v * __uint_as_float(u << 16);
            sy += v * __uint_as_float(u & 0xffff0000u);
        }
        sx += __shfl_xor(sx, 8);  sy += __shfl_xor(sy, 8);
        sx += __shfl_xor(sx, 16); sy += __shfl_xor(sy, 16);
        sx += __shfl_xor(sx, 32); sy += __shfl_xor(sy, 32);
        if (lane < 8) {
            for (int q = 0; q < ovc; ++q) {          // overflow backstop
                int4 ef = oflow[q];
                if (ef.x == node) {
                    unsigned u = *reinterpret_cast<const unsigned*>(
                        pan + (size_t)ef.y * 16 + lane * 2);
                    float v = __int_as_float(ef.z);
                    sx += v * __uint_as_float(u << 16);
                    sy += v * __uint_as_float(u & 0xffff0000u);
                }
            }
            float2 o;
            o.x = fmaxf(sx + bv.x, 0.f);
            o.y = fmaxf(sy + bv.y, 0.f);
            *reinterpret_cast<float2*>(out + (size_t)node * D + p * 16 + lane * 2) = o;
        }
    }
}

extern "C" void kernel_launch(void* const* d_in, const int* in_sizes, int n_in,
                              void* d_out, int out_size, void* d_ws, size_t ws_size,
                              hipStream_t stream) {
    const float* H    = (const float*)d_in[0];
    const float* vals = (const float*)d_in[1];
    const float* W    = (const float*)d_in[2];
    const float* b    = (const float*)d_in[3];
    const int*   src  = (const int*)d_in[4];
    const int*   dst  = (const int*)d_in[5];
    float* out = (float*)d_out;

    // workspace layout (~46 MB)
    unsigned short* HWp   = (unsigned short*)d_ws;                    // 25.6 MB (8 panels)
    unsigned short* Wfrag = HWp + (size_t)8 * N_NODES * 16;           // 32 KB
    int*  sedge     = (int*)(Wfrag + 128 * 128);                      // 9.6 MB
    int*  sedge_s   = sedge + (size_t)NFB * SUBCAP;                   // 9.6 MB (+8 pad)
    int*  off       = sedge_s + (size_t)NFB * SUBCAP + 8;             // 400 KB
    int*  cnt       = off + N_NODES;                                  // 400 KB
    int*  ccursor   = cnt + N_NODES;                                  // NFB
    int*  oflow_cnt = ccursor + NCUR;                                 // 1 (zeroed by init)
    int4* oflow     = (int4*)(((uintptr_t)(oflow_cnt + 1) + 15) & ~(uintptr_t)15);

    init_kernel<<<64, 256, 0, stream>>>(W, Wfrag, ccursor);
    fill_fine<<<FILL_BLOCKS, 1024, 0, stream>>>(src, dst, vals, ccursor,
                                                sedge, oflow, oflow_cnt);
    sort_bucket<<<NFB, 256, 0, stream>>>(sedge, ccursor, sedge_s, off, cnt);
    gemm_mfma<<<(N_NODES + 63) / 64, 256, 0, stream>>>(H, Wfrag, HWp);
    panel_gather<<<NFB * 8, 256, 0, stream>>>(HWp, sedge_s, off, cnt,
                                              oflow, oflow_cnt, b, out);
}

// Round 17
// 124.887 us; speedup vs baseline: 2.2987x; 2.2987x over previous
//
#include <hip/hip_runtime.h>

#define N_NODES  100000
#define N_EDGES  1600000
#define D        128
#define NFB      3125         // fine buckets of 32 nodes (100000/32)
#define SUBCAP   768          // fine capacity (avg 512, 11 sigma)
#define OCAP     8192         // overflow backstop
#define FCHUNK   8192         // edges per fill block -> 196 blocks
#define FILL_BLOCKS ((N_EDGES + FCHUNK - 1) / FCHUNK)   // 196
#define NPACK    ((NFB + 1) / 2)                        // 1563 packed u32 counters
#define NCUR     (NFB + 3)                              // cursors (+pad)

typedef __attribute__((ext_vector_type(8))) short bf16x8;
typedef __attribute__((ext_vector_type(4))) float f32x4;

// f32 -> bf16 (round-to-nearest-even)
__device__ __forceinline__ unsigned short f2bf(float x) {
    unsigned u = __float_as_uint(x);
    u += 0x7fffu + ((u >> 16) & 1u);
    return (unsigned short)(u >> 16);
}

// ---------------------------------------------------------------------------
// 1) fill direct 32-node fine buckets (R13/R15-proven). Block FILL_BLOCKS
//    (the +1 extra block) instead packs W into B-fragment order — gemm only
//    reads Wfrag after this kernel completes.
// ---------------------------------------------------------------------------
__global__ __launch_bounds__(1024) void fill_fine(
    const int* __restrict__ src, const int* __restrict__ dst,
    const float* __restrict__ vals, int* __restrict__ ccursor,
    int2* __restrict__ sedge, int4* __restrict__ oflow,
    int* __restrict__ oflow_cnt,
    const float* __restrict__ W, unsigned short* __restrict__ Wfrag)
{
    const int t = threadIdx.x;

    if (blockIdx.x == FILL_BLOCKS) {
        // ---- W-pack role: 16384 elems / 1024 threads = 16 each ----
#pragma unroll
        for (int q = 0; q < 16; ++q) {
            int i = q * 1024 + t;
            int k = i >> 7, n = i & 127;
            int c = n >> 4, cc = n & 15, ks = k >> 5, g = (k >> 3) & 3, j = k & 7;
            int lane = g * 16 + cc;
            Wfrag[(size_t)(((c * 4 + ks) * 64) + lane) * 8 + j] = f2bf(W[i]);
        }
        return;
    }

    __shared__ unsigned lhistP[NPACK];   // 2 x u16 counts per u32 (6.3 KB)
    __shared__ unsigned lbaseP[NPACK];

    for (int i = t; i < NPACK; i += 1024) lhistP[i] = 0;
    __syncthreads();
    const int e0 = blockIdx.x * FCHUNK;
    const int e1 = min(e0 + FCHUNK, N_EDGES);

    // phase 1: register-stage edges + packed local histogram
    int myS[8]; int myD[8]; float myV[8];
#pragma unroll
    for (int q = 0; q < 8; ++q) {
        int e = e0 + t + q * 1024;
        myS[q] = -1;
        if (e < e1) {
            int s = src[e];
            myS[q] = s;
            myD[q] = dst[e];
            myV[q] = vals[e];
            int b = s >> 5;
            atomicAdd(&lhistP[b >> 1], 1u << ((b & 1) << 4));
        }
    }
    __syncthreads();
    // phase 2: reserve global ranges, reset local cursors
    for (int i = t; i < NPACK; i += 1024) {
        unsigned p = lhistP[i];
        unsigned c0 = p & 0xffffu, c1 = p >> 16;
        unsigned b0 = c0 ? (unsigned)atomicAdd(&ccursor[2 * i], (int)c0) : 0u;
        unsigned b1 = c1 ? (unsigned)atomicAdd(&ccursor[2 * i + 1], (int)c1) : 0u;
        lbaseP[i] = (b0 & 0xffffu) | (b1 << 16);
        lhistP[i] = 0;
    }
    __syncthreads();
    // phase 3: place from registers
#pragma unroll
    for (int q = 0; q < 8; ++q) {
        if (myS[q] >= 0) {
            int s = myS[q];
            int b = s >> 5;
            unsigned sh = (unsigned)(b & 1) << 4;
            unsigned old = atomicAdd(&lhistP[b >> 1], 1u << sh);
            int pos = (int)((lbaseP[b >> 1] >> sh) & 0xffffu) +
                      (int)((old >> sh) & 0xffffu);
            if (pos < SUBCAP) {
                int2 p;
                p.x = myD[q] | ((s & 31) << 17);
                p.y = __float_as_int(myV[q]);
                sedge[(size_t)b * SUBCAP + pos] = p;
            } else {
                int oc = atomicAdd(oflow_cnt, 1);
                if (oc < OCAP) oflow[oc] = make_int4(s, myD[q], __float_as_int(myV[q]), 0);
            }
        }
    }
}

// ---------------------------------------------------------------------------
// 2) HW = H @ W via MFMA 16x16x32 bf16 (R5/R6/R13/R15-proven 64-row variant)
// ---------------------------------------------------------------------------
__global__ __launch_bounds__(256) void gemm_mfma(
    const float* __restrict__ H, const unsigned short* __restrict__ Wfrag,
    unsigned short* __restrict__ HWb)
{
    const int wid  = threadIdx.x >> 6;
    const int lane = threadIdx.x & 63;
    const int row16 = blockIdx.x * 64 + wid * 16;
    const int g = lane >> 4;

    int arow = row16 + (lane & 15);
    if (arow >= N_NODES) arow = N_NODES - 1;   // clamp (dup read, never stored)

    f32x4 acc[8];
#pragma unroll
    for (int c = 0; c < 8; ++c) acc[c] = (f32x4){0.f, 0.f, 0.f, 0.f};

#pragma unroll
    for (int ks = 0; ks < 4; ++ks) {
        const float* ap = H + (size_t)arow * D + ks * 32 + g * 8;
        float4 a0 = *reinterpret_cast<const float4*>(ap);
        float4 a1 = *reinterpret_cast<const float4*>(ap + 4);
        bf16x8 af;
        af[0] = (short)f2bf(a0.x); af[1] = (short)f2bf(a0.y);
        af[2] = (short)f2bf(a0.z); af[3] = (short)f2bf(a0.w);
        af[4] = (short)f2bf(a1.x); af[5] = (short)f2bf(a1.y);
        af[6] = (short)f2bf(a1.z); af[7] = (short)f2bf(a1.w);
#pragma unroll
        for (int c = 0; c < 8; ++c) {
            bf16x8 bf = *reinterpret_cast<const bf16x8*>(
                Wfrag + (size_t)((c * 4 + ks) * 64 + lane) * 8);
            acc[c] = __builtin_amdgcn_mfma_f32_16x16x32_bf16(af, bf, acc[c], 0, 0, 0);
        }
    }

#pragma unroll
    for (int c = 0; c < 8; ++c) {
#pragma unroll
        for (int r = 0; r < 4; ++r) {
            int orow = row16 + g * 4 + r;
            if (orow < N_NODES)
                HWb[(size_t)orow * D + c * 16 + (lane & 15)] = f2bf(acc[c][r]);
        }
    }
}

// ---------------------------------------------------------------------------
// 3) fused counting-sort (register-staged, into LDS) + gather + bias + relu.
//    One WG per 32-node fine bucket, 256 threads (R7/R12/R13/R15-proven).
// ---------------------------------------------------------------------------
__global__ __launch_bounds__(256) void sort_gather(
    const unsigned short* __restrict__ HWb, const int2* __restrict__ sedge,
    const int* __restrict__ ccursor, const int4* __restrict__ oflow,
    const int* __restrict__ oflow_cnt, const float* __restrict__ bias,
    float* __restrict__ out)
{
    __shared__ int2 eLds[SUBCAP];   // 6 KB
    __shared__ int h[32];
    __shared__ int ex[32];
    __shared__ int cur[32];
    const int bkt = blockIdx.x;
    const int t = threadIdx.x;
    const size_t base = (size_t)bkt * SUBCAP;
    const int cnt = min(ccursor[bkt], SUBCAP);

    if (t < 32) h[t] = 0;
    __syncthreads();

    // pass 1: load edges to registers + histogram (SUBCAP/256 = 3 per thread)
    int2 myE[3]; int myR[3];
#pragma unroll
    for (int q = 0; q < 3; ++q) {
        int j = t + q * 256;
        myR[q] = -1;
        if (j < cnt) {
            myE[q] = sedge[base + j];
            myR[q] = (myE[q].x >> 17) & 31;
            atomicAdd(&h[myR[q]], 1);
        }
    }
    __syncthreads();
    // exclusive scan over 32 counters (first wave, shfl)
    if (t < 32) {
        int v = h[t];
        int x = v;
        for (int off = 1; off < 32; off <<= 1) {
            int y = __shfl_up(x, off);
            if (t >= off) x += y;
        }
        ex[t] = x - v;
        cur[t] = 0;
    }
    __syncthreads();
    // pass 2: place sorted into LDS from registers (strip src bits)
#pragma unroll
    for (int q = 0; q < 3; ++q) {
        if (myR[q] >= 0) {
            int pos = ex[myR[q]] + atomicAdd(&cur[myR[q]], 1);
            int2 e;
            e.x = myE[q].x & 0x1FFFF;
            e.y = myE[q].y;
            eLds[pos] = e;
        }
    }
    __syncthreads();

    // gather: wave w handles local nodes w, w+4, ...
    const int wid = t >> 6, lane = t & 63;
    const int ovc = *oflow_cnt;                       // normally 0
    const float2 bv = *reinterpret_cast<const float2*>(bias + lane * 2);
    for (int ln = wid; ln < 32; ln += 4) {
        int node = bkt * 32 + ln;
        const int j0 = ex[ln], j1 = ex[ln] + h[ln];
        float ax = 0.f, ay = 0.f, bx = 0.f, by = 0.f;
        float cx = 0.f, cy = 0.f, dx = 0.f, dy = 0.f;
        int j = j0;
        for (; j + 4 <= j1; j += 4) {
            int2 e0 = eLds[j],     e1 = eLds[j + 1];
            int2 e2 = eLds[j + 2], e3 = eLds[j + 3];
            unsigned u0 = *reinterpret_cast<const unsigned*>(HWb + (size_t)e0.x * D + lane * 2);
            unsigned u1 = *reinterpret_cast<const unsigned*>(HWb + (size_t)e1.x * D + lane * 2);
            unsigned u2 = *reinterpret_cast<const unsigned*>(HWb + (size_t)e2.x * D + lane * 2);
            unsigned u3 = *reinterpret_cast<const unsigned*>(HWb + (size_t)e3.x * D + lane * 2);
            float v0 = __int_as_float(e0.y), v1 = __int_as_float(e1.y);
            float v2 = __int_as_float(e2.y), v3 = __int_as_float(e3.y);
            ax += v0 * __uint_as_float(u0 << 16);
            ay += v0 * __uint_as_float(u0 & 0xffff0000u);
            bx += v1 * __uint_as_float(u1 << 16);
            by += v1 * __uint_as_float(u1 & 0xffff0000u);
            cx += v2 * __uint_as_float(u2 << 16);
            cy += v2 * __uint_as_float(u2 & 0xffff0000u);
            dx += v3 * __uint_as_float(u3 << 16);
            dy += v3 * __uint_as_float(u3 & 0xffff0000u);
        }
        for (; j < j1; ++j) {
            int2 e = eLds[j];
            unsigned u = *reinterpret_cast<const unsigned*>(HWb + (size_t)e.x * D + lane * 2);
            float v = __int_as_float(e.y);
            ax += v * __uint_as_float(u << 16);
            ay += v * __uint_as_float(u & 0xffff0000u);
        }
        // overflow backstop (ovc normally 0)
        for (int q = 0; q < ovc; ++q) {
            int4 e = oflow[q];
            if (e.x == node) {
                unsigned u = *reinterpret_cast<const unsigned*>(HWb + (size_t)e.y * D + lane * 2);
                float v = __int_as_float(e.z);
                ax += v * __uint_as_float(u << 16);
                ay += v * __uint_as_float(u & 0xffff0000u);
            }
        }
        float2 o;
        o.x = fmaxf((ax + bx) + (cx + dx) + bv.x, 0.f);
        o.y = fmaxf((ay + by) + (cy + dy) + bv.y, 0.f);
        *reinterpret_cast<float2*>(out + (size_t)node * D + lane * 2) = o;
    }
}

extern "C" void kernel_launch(void* const* d_in, const int* in_sizes, int n_in,
                              void* d_out, int out_size, void* d_ws, size_t ws_size,
                              hipStream_t stream) {
    const float* H    = (const float*)d_in[0];
    const float* vals = (const float*)d_in[1];
    const float* W    = (const float*)d_in[2];
    const float* b    = (const float*)d_in[3];
    const int*   src  = (const int*)d_in[4];
    const int*   dst  = (const int*)d_in[5];
    float* out = (float*)d_out;

    // workspace layout (~45 MB)
    unsigned short* HWb   = (unsigned short*)d_ws;                    // 25.6 MB
    unsigned short* Wfrag = HWb + (size_t)N_NODES * D;                // 32 KB
    int2* sedge     = (int2*)(Wfrag + 128 * 128);                     // 19.2 MB
    int*  ccursor   = (int*)(sedge + (size_t)NFB * SUBCAP);           // NFB
    int*  oflow_cnt = ccursor + NCUR;                                 // 1
    int4* oflow     = (int4*)(((uintptr_t)(oflow_cnt + 1) + 15) & ~(uintptr_t)15); // 128 KB

    // zero cursors + oflow_cnt (contiguous small region)
    hipMemsetAsync(ccursor, 0, (NCUR + 2) * sizeof(int), stream);

    fill_fine<<<FILL_BLOCKS + 1, 1024, 0, stream>>>(src, dst, vals, ccursor,
                                                    sedge, oflow, oflow_cnt,
                                                    W, Wfrag);
    gemm_mfma<<<(N_NODES + 63) / 64, 256, 0, stream>>>(H, Wfrag, HWb);
    sort_gather<<<NFB, 256, 0, stream>>>(HWb, sedge, ccursor, oflow,
                                         oflow_cnt, b, out);
}

// Round 18
// 122.026 us; speedup vs baseline: 2.3526x; 1.0234x over previous
//
#include <hip/hip_runtime.h>

#define N_NODES  100000
#define N_EDGES  1600000
#define D        128
#define NFB      3125         // fine buckets of 32 nodes (100000/32)
#define SUBCAP   768          // fine capacity (avg 512, 11 sigma)
#define OCAP     8192         // overflow backstop
#define FCHUNK   8192         // edges per fill block -> 196 blocks
#define FILL_BLOCKS ((N_EDGES + FCHUNK - 1) / FCHUNK)   // 196
#define NPACK    ((NFB + 1) / 2)                        // 1563 packed u32 counters
#define NCUR     (NFB + 3)                              // cursors (+pad)

typedef __attribute__((ext_vector_type(8))) short bf16x8;
typedef __attribute__((ext_vector_type(4))) float f32x4;

// f32 -> bf16 (round-to-nearest-even)
__device__ __forceinline__ unsigned short f2bf(float x) {
    unsigned u = __float_as_uint(x);
    u += 0x7fffu + ((u >> 16) & 1u);
    return (unsigned short)(u >> 16);
}

// ---------------------------------------------------------------------------
// 0) init: zero ccursor+oflow_cnt AND pack W into B-fragment order
// ---------------------------------------------------------------------------
__global__ __launch_bounds__(256) void init_kernel(
    const float* __restrict__ W, unsigned short* __restrict__ Wfrag,
    int* __restrict__ ccursor)
{
    int t = blockIdx.x * 256 + threadIdx.x;
    if (t <= NCUR) ccursor[t] = 0;              // cursors + oflow_cnt
    // W fragment packing: 128*128 = 16384 = 64 blocks * 256 threads
    int k = t >> 7, n = t & 127;
    int c = n >> 4, cc = n & 15, ks = k >> 5, g = (k >> 3) & 3, j = k & 7;
    int lane = g * 16 + cc;
    Wfrag[(size_t)(((c * 4 + ks) * 64) + lane) * 8 + j] = f2bf(W[t]);
}

// ---------------------------------------------------------------------------
// 1) fill direct 32-node fine buckets. 1024 threads/block (16 waves -> TLP),
//    packed-u16 LDS counters, register-staged edges (R13/R15-proven).
// ---------------------------------------------------------------------------
__global__ __launch_bounds__(1024) void fill_fine(
    const int* __restrict__ src, const int* __restrict__ dst,
    const float* __restrict__ vals, int* __restrict__ ccursor,
    int2* __restrict__ sedge, int4* __restrict__ oflow,
    int* __restrict__ oflow_cnt)
{
    __shared__ unsigned lhistP[NPACK];   // 2 x u16 counts per u32 (6.3 KB)
    __shared__ unsigned lbaseP[NPACK];
    const int t = threadIdx.x;

    for (int i = t; i < NPACK; i += 1024) lhistP[i] = 0;
    __syncthreads();
    const int e0 = blockIdx.x * FCHUNK;
    const int e1 = min(e0 + FCHUNK, N_EDGES);

    // phase 1: register-stage edges + packed local histogram
    int myS[8]; int myD[8]; float myV[8];
#pragma unroll
    for (int q = 0; q < 8; ++q) {
        int e = e0 + t + q * 1024;
        myS[q] = -1;
        if (e < e1) {
            int s = src[e];
            myS[q] = s;
            myD[q] = dst[e];
            myV[q] = vals[e];
            int b = s >> 5;
            atomicAdd(&lhistP[b >> 1], 1u << ((b & 1) << 4));
        }
    }
    __syncthreads();
    // phase 2: reserve global ranges, reset local cursors
    for (int i = t; i < NPACK; i += 1024) {
        unsigned p = lhistP[i];
        unsigned c0 = p & 0xffffu, c1 = p >> 16;
        unsigned b0 = c0 ? (unsigned)atomicAdd(&ccursor[2 * i], (int)c0) : 0u;
        unsigned b1 = c1 ? (unsigned)atomicAdd(&ccursor[2 * i + 1], (int)c1) : 0u;
        lbaseP[i] = (b0 & 0xffffu) | (b1 << 16);
        lhistP[i] = 0;
    }
    __syncthreads();
    // phase 3: place from registers
#pragma unroll
    for (int q = 0; q < 8; ++q) {
        if (myS[q] >= 0) {
            int s = myS[q];
            int b = s >> 5;
            unsigned sh = (unsigned)(b & 1) << 4;
            unsigned old = atomicAdd(&lhistP[b >> 1], 1u << sh);
            int pos = (int)((lbaseP[b >> 1] >> sh) & 0xffffu) +
                      (int)((old >> sh) & 0xffffu);
            if (pos < SUBCAP) {
                int2 p;
                p.x = myD[q] | ((s & 31) << 17);
                p.y = __float_as_int(myV[q]);
                sedge[(size_t)b * SUBCAP + pos] = p;
            } else {
                int oc = atomicAdd(oflow_cnt, 1);
                if (oc < OCAP) oflow[oc] = make_int4(s, myD[q], __float_as_int(myV[q]), 0);
            }
        }
    }
}

// ---------------------------------------------------------------------------
// 2) HW = H @ W via MFMA 16x16x32 bf16 (R5/R6/R13/R15-proven 64-row variant)
// ---------------------------------------------------------------------------
__global__ __launch_bounds__(256) void gemm_mfma(
    const float* __restrict__ H, const unsigned short* __restrict__ Wfrag,
    unsigned short* __restrict__ HWb)
{
    const int wid  = threadIdx.x >> 6;
    const int lane = threadIdx.x & 63;
    const int row16 = blockIdx.x * 64 + wid * 16;
    const int g = lane >> 4;

    int arow = row16 + (lane & 15);
    if (arow >= N_NODES) arow = N_NODES - 1;   // clamp (dup read, never stored)

    f32x4 acc[8];
#pragma unroll
    for (int c = 0; c < 8; ++c) acc[c] = (f32x4){0.f, 0.f, 0.f, 0.f};

#pragma unroll
    for (int ks = 0; ks < 4; ++ks) {
        const float* ap = H + (size_t)arow * D + ks * 32 + g * 8;
        float4 a0 = *reinterpret_cast<const float4*>(ap);
        float4 a1 = *reinterpret_cast<const float4*>(ap + 4);
        bf16x8 af;
        af[0] = (short)f2bf(a0.x); af[1] = (short)f2bf(a0.y);
        af[2] = (short)f2bf(a0.z); af[3] = (short)f2bf(a0.w);
        af[4] = (short)f2bf(a1.x); af[5] = (short)f2bf(a1.y);
        af[6] = (short)f2bf(a1.z); af[7] = (short)f2bf(a1.w);
#pragma unroll
        for (int c = 0; c < 8; ++c) {
            bf16x8 bf = *reinterpret_cast<const bf16x8*>(
                Wfrag + (size_t)((c * 4 + ks) * 64 + lane) * 8);
            acc[c] = __builtin_amdgcn_mfma_f32_16x16x32_bf16(af, bf, acc[c], 0, 0, 0);
        }
    }

#pragma unroll
    for (int c = 0; c < 8; ++c) {
#pragma unroll
        for (int r = 0; r < 4; ++r) {
            int orow = row16 + g * 4 + r;
            if (orow < N_NODES)
                HWb[(size_t)orow * D + c * 16 + (lane & 15)] = f2bf(acc[c][r]);
        }
    }
}

// ---------------------------------------------------------------------------
// 3) fused counting-sort (register-staged, into LDS) + gather + bias + relu.
//    One WG per 32-node fine bucket, 256 threads (R7/R12/R13/R15-proven).
// ---------------------------------------------------------------------------
__global__ __launch_bounds__(256) void sort_gather(
    const unsigned short* __restrict__ HWb, const int2* __restrict__ sedge,
    const int* __restrict__ ccursor, const int4* __restrict__ oflow,
    const int* __restrict__ oflow_cnt, const float* __restrict__ bias,
    float* __restrict__ out)
{
    __shared__ int2 eLds[SUBCAP];   // 6 KB
    __shared__ int h[32];
    __shared__ int ex[32];
    __shared__ int cur[32];
    const int bkt = blockIdx.x;
    const int t = threadIdx.x;
    const size_t base = (size_t)bkt * SUBCAP;
    const int cnt = min(ccursor[bkt], SUBCAP);

    if (t < 32) h[t] = 0;
    __syncthreads();

    // pass 1: load edges to registers + histogram (SUBCAP/256 = 3 per thread)
    int2 myE[3]; int myR[3];
#pragma unroll
    for (int q = 0; q < 3; ++q) {
        int j = t + q * 256;
        myR[q] = -1;
        if (j < cnt) {
            myE[q] = sedge[base + j];
            myR[q] = (myE[q].x >> 17) & 31;
            atomicAdd(&h[myR[q]], 1);
        }
    }
    __syncthreads();
    // exclusive scan over 32 counters (first wave, shfl)
    if (t < 32) {
        int v = h[t];
        int x = v;
        for (int off = 1; off < 32; off <<= 1) {
            int y = __shfl_up(x, off);
            if (t >= off) x += y;
        }
        ex[t] = x - v;
        cur[t] = 0;
    }
    __syncthreads();
    // pass 2: place sorted into LDS from registers (strip src bits)
#pragma unroll
    for (int q = 0; q < 3; ++q) {
        if (myR[q] >= 0) {
            int pos = ex[myR[q]] + atomicAdd(&cur[myR[q]], 1);
            int2 e;
            e.x = myE[q].x & 0x1FFFF;
            e.y = myE[q].y;
            eLds[pos] = e;
        }
    }
    __syncthreads();

    // gather: wave w handles local nodes w, w+4, ...
    const int wid = t >> 6, lane = t & 63;
    const int ovc = *oflow_cnt;                       // normally 0
    const float2 bv = *reinterpret_cast<const float2*>(bias + lane * 2);
    for (int ln = wid; ln < 32; ln += 4) {
        int node = bkt * 32 + ln;
        const int j0 = ex[ln], j1 = ex[ln] + h[ln];
        float ax = 0.f, ay = 0.f, bx = 0.f, by = 0.f;
        float cx = 0.f, cy = 0.f, dx = 0.f, dy = 0.f;
        int j = j0;
        for (; j + 4 <= j1; j += 4) {
            int2 e0 = eLds[j],     e1 = eLds[j + 1];
            int2 e2 = eLds[j + 2], e3 = eLds[j + 3];
            unsigned u0 = *reinterpret_cast<const unsigned*>(HWb + (size_t)e0.x * D + lane * 2);
            unsigned u1 = *reinterpret_cast<const unsigned*>(HWb + (size_t)e1.x * D + lane * 2);
            unsigned u2 = *reinterpret_cast<const unsigned*>(HWb + (size_t)e2.x * D + lane * 2);
            unsigned u3 = *reinterpret_cast<const unsigned*>(HWb + (size_t)e3.x * D + lane * 2);
            float v0 = __int_as_float(e0.y), v1 = __int_as_float(e1.y);
            float v2 = __int_as_float(e2.y), v3 = __int_as_float(e3.y);
            ax += v0 * __uint_as_float(u0 << 16);
            ay += v0 * __uint_as_float(u0 & 0xffff0000u);
            bx += v1 * __uint_as_float(u1 << 16);
            by += v1 * __uint_as_float(u1 & 0xffff0000u);
            cx += v2 * __uint_as_float(u2 << 16);
            cy += v2 * __uint_as_float(u2 & 0xffff0000u);
            dx += v3 * __uint_as_float(u3 << 16);
            dy += v3 * __uint_as_float(u3 & 0xffff0000u);
        }
        for (; j < j1; ++j) {
            int2 e = eLds[j];
            unsigned u = *reinterpret_cast<const unsigned*>(HWb + (size_t)e.x * D + lane * 2);
            float v = __int_as_float(e.y);
            ax += v * __uint_as_float(u << 16);
            ay += v * __uint_as_float(u & 0xffff0000u);
        }
        // overflow backstop (ovc normally 0)
        for (int q = 0; q < ovc; ++q) {
            int4 e = oflow[q];
            if (e.x == node) {
                unsigned u = *reinterpret_cast<const unsigned*>(HWb + (size_t)e.y * D + lane * 2);
                float v = __int_as_float(e.z);
                ax += v * __uint_as_float(u << 16);
                ay += v * __uint_as_float(u & 0xffff0000u);
            }
        }
        float2 o;
        o.x = fmaxf((ax + bx) + (cx + dx) + bv.x, 0.f);
        o.y = fmaxf((ay + by) + (cy + dy) + bv.y, 0.f);
        *reinterpret_cast<float2*>(out + (size_t)node * D + lane * 2) = o;
    }
}

extern "C" void kernel_launch(void* const* d_in, const int* in_sizes, int n_in,
                              void* d_out, int out_size, void* d_ws, size_t ws_size,
                              hipStream_t stream) {
    const float* H    = (const float*)d_in[0];
    const float* vals = (const float*)d_in[1];
    const float* W    = (const float*)d_in[2];
    const float* b    = (const float*)d_in[3];
    const int*   src  = (const int*)d_in[4];
    const int*   dst  = (const int*)d_in[5];
    float* out = (float*)d_out;

    // workspace layout (~45 MB)
    unsigned short* HWb   = (unsigned short*)d_ws;                    // 25.6 MB
    unsigned short* Wfrag = HWb + (size_t)N_NODES * D;                // 32 KB
    int2* sedge     = (int2*)(Wfrag + 128 * 128);                     // 19.2 MB
    int*  ccursor   = (int*)(sedge + (size_t)NFB * SUBCAP);           // NFB
    int*  oflow_cnt = ccursor + NCUR;                                 // 1 (zeroed by init)
    int4* oflow     = (int4*)(((uintptr_t)(oflow_cnt + 1) + 15) & ~(uintptr_t)15); // 128 KB

    init_kernel<<<64, 256, 0, stream>>>(W, Wfrag, ccursor);
    fill_fine<<<FILL_BLOCKS, 1024, 0, stream>>>(src, dst, vals, ccursor,
                                                sedge, oflow, oflow_cnt);
    gemm_mfma<<<(N_NODES + 63) / 64, 256, 0, stream>>>(H, Wfrag, HWb);
    sort_gather<<<NFB, 256, 0, stream>>>(HWb, sedge, ccursor, oflow,
                                         oflow_cnt, b, out);
}